// Round 11
// baseline (74.500 us; speedup 1.0000x reference)
//
#include <hip/hip_runtime.h>
#include <hip/hip_bf16.h>

typedef __bf16 bf16_t;
typedef bf16_t bf16x8 __attribute__((ext_vector_type(8)));
typedef float f32x4 __attribute__((ext_vector_type(4)));
typedef unsigned long long u64_t;

#define TH 16     // total heads
#define CH 4      // contextual heads
#define DD 64     // head dim
#define SJ 2048   // seq len (harness-fixed)
#define SP (SJ + 4)                   // padded LDS row stride
#define RROWS 8                       // ctx rows per block -> ~33 KiB LDS
#define KT (SJ/16)                    // 128 col-tiles per head
#define NCTX (CH*SJ/RROWS)            // 1024 ctx blocks
#define AROWS 16                      // alibi rows per block
#define NALIBI ((TH-CH)*SJ/AROWS)     // 1536 alibi blocks
#define HEADSTART 512                 // leading pure-alibi blocks (store head-start)
#define NBLK (NCTX + NALIBI)          // 2560
#define WSK_BYTES ((size_t)CH*KT*2*64*16)     // 1 MiB: K in B-fragment order

__device__ __forceinline__ float sigmoidf_(float x) {
    return __builtin_amdgcn_rcpf(1.0f + __expf(-x));
}

__device__ __forceinline__ float bsel(u64_t u, int e) {
    return __uint_as_float((((unsigned int)(u >> (16 * e)) & 0xffffu) << 16));
}

// Convert ctx-head K to bf16 in MFMA-B-fragment order:
// frag index t = ((h*128 + ct)*2 + kk)*64 + lane ; each frag elem 8 bf16.
__global__ __launch_bounds__(256) void prep_kernel(
    const float* __restrict__ k, bf16_t* __restrict__ wsk)
{
    const int t    = (int)blockIdx.x * 256 + (int)threadIdx.x;  // 0..65535
    const int h    = t >> 14;
    const int ct   = (t >> 7) & 127;
    const int kk   = (t >> 6) & 1;
    const int lane = t & 63;
    const int col  = ct * 16 + (lane & 15);
    const int db   = kk * 32 + (lane >> 4) * 8;
    const float* p = k + ((size_t)h * SJ + col) * DD + db;
    f32x4 v0 = *(const f32x4*)p;
    f32x4 v1 = *(const f32x4*)(p + 4);
    bf16x8 o;
    #pragma unroll
    for (int e = 0; e < 4; ++e) { o[e] = (bf16_t)v0[e]; o[e + 4] = (bf16_t)v1[e]; }
    *(bf16x8*)(wsk + (size_t)t * 8) = o;
}

__global__ __launch_bounds__(512, 4) void fused_kernel(
    const float* __restrict__ q, const float* __restrict__ k,
    const bf16_t* __restrict__ wsk, int use_ws,
    const float* __restrict__ cab, const int* __restrict__ offp,
    const int* __restrict__ prep, float* __restrict__ out)
{
    __shared__ bf16_t Smb[RROWS][SP];     // ~32.1 KiB
    __shared__ float tot[RROWS][8];
    __shared__ float pd_in[RROWS], pd_ex[RROWS];
    const int tid  = (int)threadIdx.x;
    const int lane = tid & 63;
    const int w    = tid >> 6;            // wave 0..7
    const int offset = offp[0];
    const int prefix = prep[0];
    const int bx = (int)blockIdx.x;

    // ---- dispatch-order skew: alibi head-start, then 1:1 ctx/alibi interleave
    int ctx_id = -1, al_id;
    if (bx < HEADSTART) {
        al_id = bx;
    } else {
        const int t = bx - HEADSTART;
        if ((t & 1) == 0) ctx_id = t >> 1;
        else              al_id  = HEADSTART + (t >> 1);
    }

    if (ctx_id >= 0) {
        // ---------------- contextual strip: 8 rows ----------------
        const int id = ctx_id;            // 0..1023
        const int h  = id >> 8;           // 0..3
        const int r0 = (id & 255) * RROWS;
        const float* qh = q + (size_t)h * SJ * DD;
        const float* kh = k + (size_t)h * SJ * DD;

        // ---- Phase A: dots via mfma_f32_16x16x32_bf16 (A rows duplicated 2x),
        // sigmoid -> Smb for the 8 real rows.
        bf16x8 afrag[2];
        {
            const int row   = r0 + ((lane & 15) & 7);  // rows 8..15 dup 0..7
            const int dbase = (lane >> 4) * 8;
            const float* qp = qh + (size_t)row * DD + dbase;
            #pragma unroll
            for (int kk = 0; kk < 2; ++kk) {
                f32x4 v0 = *(const f32x4*)(qp + kk * 32);
                f32x4 v1 = *(const f32x4*)(qp + kk * 32 + 4);
                #pragma unroll
                for (int e = 0; e < 4; ++e) {
                    afrag[kk][e]     = (bf16_t)v0[e];
                    afrag[kk][e + 4] = (bf16_t)v1[e];
                }
            }
        }
        if (tid < RROWS) { pd_in[tid] = 0.f; pd_ex[tid] = 0.f; }
        // wave w computes col tiles in [w*256, (w+1)*256)
        const int rb = (lane >> 4) * 4;   // D row base; rb>=8 -> duplicate rows
        for (int t = 0; t < 16; ++t) {
            const int c0 = w * 256 + t * 16;
            f32x4 acc = {0.f, 0.f, 0.f, 0.f};
            if (use_ws) {
                const size_t fb = (((size_t)h * KT + (c0 >> 4)) * 2) * 64 + lane;
                #pragma unroll
                for (int kk = 0; kk < 2; ++kk) {
                    bf16x8 bfrag = *(const bf16x8*)(wsk + (fb + (size_t)kk * 64) * 8);
                    acc = __builtin_amdgcn_mfma_f32_16x16x32_bf16(afrag[kk], bfrag, acc, 0, 0, 0);
                }
            } else {
                #pragma unroll
                for (int kk = 0; kk < 2; ++kk) {
                    const int col = c0 + (lane & 15);
                    const int db  = kk * 32 + (lane >> 4) * 8;
                    const float* p = kh + (size_t)col * DD + db;
                    f32x4 v0 = *(const f32x4*)(p);
                    f32x4 v1 = *(const f32x4*)(p + 4);
                    bf16x8 bfrag;
                    #pragma unroll
                    for (int e = 0; e < 4; ++e) {
                        bfrag[e]     = (bf16_t)v0[e];
                        bfrag[e + 4] = (bf16_t)v1[e];
                    }
                    acc = __builtin_amdgcn_mfma_f32_16x16x32_bf16(afrag[kk], bfrag, acc, 0, 0, 0);
                }
            }
            if (rb < RROWS) {
                const int ccol = c0 + (lane & 15);
                #pragma unroll
                for (int m = 0; m < 4; ++m)
                    Smb[rb + m][ccol] = (bf16_t)sigmoidf_(acc[m] * 0.125f);
            }
        }
        __syncthreads();

        // ---- Phase B: wave w owns cols [w*256, w*256+256) of all 8 rows.
        // All barriers before any global store.
        const float slope = exp2f(-0.5f * (float)(h + 1));
        const float cabv  = cab[h];
        const int cb = w * 256 + lane * 4;
        u64_t u[RROWS];
        float base_[RROWS];
        #pragma unroll
        for (int rl = 0; rl < RROWS; ++rl) {
            u[rl] = *(const u64_t*)(&Smb[rl][cb]);
            const float i3 = ((bsel(u[rl], 0) + bsel(u[rl], 1))
                            + (bsel(u[rl], 2) + bsel(u[rl], 3)));
            float x = i3;
            #pragma unroll
            for (int d = 1; d < 64; d <<= 1) {
                float y = __shfl_up(x, d);
                if (lane >= d) x += y;
            }
            if (lane == 63) tot[rl][w] = x;
            base_[rl] = x - i3;           // lane-exclusive within segment
        }
        __syncthreads();                  // tot ready
        #pragma unroll
        for (int rl = 0; rl < RROWS; ++rl) {
            float b = 0.f;
            #pragma unroll
            for (int s = 0; s < 7; ++s)
                b += (s < w) ? tot[rl][s] : 0.f;
            base_[rl] += b;               // = P[cb-1] (exclusive total)
            const int rg = r0 + rl, dg = rg + offset;
            const int cin = dg < SJ ? dg : SJ - 1;
            const int cex = (dg - 1) < SJ ? dg - 1 : SJ - 1;
            if (dg >= 0 && (unsigned)(cin - cb) < 4u) {
                const int e = cin - cb;
                float pi = bsel(u[rl], 0);
                if (e > 0) pi += bsel(u[rl], 1);
                if (e > 1) pi += bsel(u[rl], 2);
                if (e > 2) pi += bsel(u[rl], 3);
                pd_in[rl] = base_[rl] + pi;
            }
            if (dg >= 1 && (unsigned)(cex - cb) < 4u) {
                const int e = cex - cb;
                float pi = bsel(u[rl], 0);
                if (e > 0) pi += bsel(u[rl], 1);
                if (e > 1) pi += bsel(u[rl], 2);
                if (e > 2) pi += bsel(u[rl], 3);
                pd_ex[rl] = base_[rl] + pi;
            }
        }
        __syncthreads();                  // pd ready; LAST barrier
        // ---- Phase C: pure store tail, fire-and-forget
        #pragma unroll
        for (int rl = 0; rl < RROWS; ++rl) {
            const int rg = r0 + rl, dg = rg + offset;
            const float pdin = pd_in[rl];
            const float pdex = pd_ex[rl];
            const bool rpre = dg < prefix;
            const float b  = base_[rl];
            const float i0 = b  + bsel(u[rl], 0);
            const float i1 = i0 + bsel(u[rl], 1);
            const float i2 = i1 + bsel(u[rl], 2);
            const float i3 = i2 + bsel(u[rl], 3);
            const float Pc[4] = {i0, i1, i2, i3};
            const float Pm[4] = {b, i0, i1, i2};
            float* orow = out + ((size_t)h * SJ + rg) * (size_t)SJ;
            f32x4 o;
            #pragma unroll
            for (int e = 0; e < 4; ++e) {
                const int c = cb + e;
                const float cpos = (c > dg) ? -(Pc[e] - pdin)
                                 : (c < dg) ? -(pdex - Pm[e]) : 0.f;
                const bool cross = (c < prefix) != rpre;
                o[e] = cross ? cabv : slope * cpos;
            }
            *(f32x4*)(orow + cb) = o;
        }
    } else {
        // ---------------- ALiBi block: 16 rows, pure write ----------------
        const int id = al_id;                     // 0..1535
        const int h  = CH + (id >> 7);            // 4..15
        const int r0 = (id & 127) * AROWS;
        const float slope = exp2f(-0.5f * (float)(h + 1));
        const float cabv  = cab[h];
        #pragma unroll
        for (int rr = 0; rr < 2; ++rr) {
            const int rg = r0 + rr * 8 + w;
            const int dg = rg + offset;
            const bool rpre = dg < prefix;
            float* orow = out + ((size_t)h * SJ + rg) * (size_t)SJ;
            #pragma unroll
            for (int s = 0; s < 8; ++s) {
                const int cb = s * 256 + lane * 4;
                f32x4 o;
                #pragma unroll
                for (int e = 0; e < 4; ++e) {
                    const int c = cb + e;
                    const float v = -fabsf((float)(c - dg)) * slope;
                    const bool cross = (c < prefix) != rpre;
                    o[e] = cross ? cabv : v;
                }
                *(f32x4*)(orow + cb) = o;
            }
        }
    }
}

extern "C" void kernel_launch(void* const* d_in, const int* in_sizes, int n_in,
                              void* d_out, int out_size, void* d_ws, size_t ws_size,
                              hipStream_t stream) {
    const float* q    = (const float*)d_in[0];
    const float* k    = (const float*)d_in[1];
    const float* cab  = (const float*)d_in[2];
    const int*   offp = (const int*)d_in[5];
    const int*   prep = (const int*)d_in[6];
    float* out = (float*)d_out;
    bf16_t* wsk = (bf16_t*)d_ws;

    const int use_ws = (ws_size >= WSK_BYTES) ? 1 : 0;
    if (use_ws)
        prep_kernel<<<dim3(256), dim3(256), 0, stream>>>(k, wsk);
    fused_kernel<<<dim3(NBLK), dim3(512), 0, stream>>>(q, k, wsk, use_ws,
                                                       cab, offp, prep, out);
}

// Round 12
// 63.811 us; speedup vs baseline: 1.1675x; 1.1675x over previous
//
#include <hip/hip_runtime.h>
#include <hip/hip_bf16.h>

typedef __bf16 bf16_t;
typedef bf16_t bf16x8 __attribute__((ext_vector_type(8)));
typedef float f32x4 __attribute__((ext_vector_type(4)));
typedef unsigned long long u64_t;

#define TH 16     // total heads
#define CH 4      // contextual heads
#define DD 64     // head dim
#define SJ 2048   // seq len (harness-fixed)
#define SP (SJ + 4)                   // padded LDS row stride
#define RROWS 8                       // ctx rows per block -> ~33 KiB LDS
#define KT (SJ/16)                    // 128 col-tiles per head
#define NCTX (CH*SJ/RROWS)            // 1024 ctx blocks
#define AROWS 16                      // alibi rows per block
#define NALIBI ((TH-CH)*SJ/AROWS)     // 1536
#define NBLK (NCTX + NALIBI)          // 2560; period-5: 2 ctx : 3 alibi (5 coprime 8 XCDs)
#define WSK_BYTES ((size_t)CH*KT*2*64*16)     // 1 MiB: K in B-fragment order

__device__ __forceinline__ float sigmoidf_(float x) {
    return __builtin_amdgcn_rcpf(1.0f + __expf(-x));
}

__device__ __forceinline__ float bsel(u64_t u, int e) {
    return __uint_as_float((((unsigned int)(u >> (16 * e)) & 0xffffu) << 16));
}

// Convert ctx-head K to bf16 in MFMA-B-fragment order:
// frag index t = ((h*128 + ct)*2 + kk)*64 + lane ; each frag elem 8 bf16.
__global__ __launch_bounds__(256) void prep_kernel(
    const float* __restrict__ k, bf16_t* __restrict__ wsk)
{
    const int t    = (int)blockIdx.x * 256 + (int)threadIdx.x;  // 0..65535
    const int h    = t >> 14;
    const int ct   = (t >> 7) & 127;
    const int kk   = (t >> 6) & 1;
    const int lane = t & 63;
    const int col  = ct * 16 + (lane & 15);
    const int db   = kk * 32 + (lane >> 4) * 8;
    const float* p = k + ((size_t)h * SJ + col) * DD + db;
    f32x4 v0 = *(const f32x4*)p;
    f32x4 v1 = *(const f32x4*)(p + 4);
    bf16x8 o;
    #pragma unroll
    for (int e = 0; e < 4; ++e) { o[e] = (bf16_t)v0[e]; o[e + 4] = (bf16_t)v1[e]; }
    *(bf16x8*)(wsk + (size_t)t * 8) = o;
}

__global__ __launch_bounds__(512, 4) void fused_kernel(
    const float* __restrict__ q, const float* __restrict__ k,
    const bf16_t* __restrict__ wsk, int use_ws,
    const float* __restrict__ cab, const int* __restrict__ offp,
    const int* __restrict__ prep, float* __restrict__ out)
{
    __shared__ bf16_t Smb[RROWS][SP];     // ~32.1 KiB
    __shared__ float tot[RROWS][8];
    __shared__ float pd_in[RROWS], pd_ex[RROWS];
    const int tid  = (int)threadIdx.x;
    const int lane = tid & 63;
    const int w    = tid >> 6;            // wave 0..7
    const int offset = offp[0];
    const int prefix = prep[0];
    const int bx = (int)blockIdx.x;
    const int m5 = bx % 5;

    if (m5 < 2) {
        // ---------------- contextual strip: 8 rows ----------------
        const int id = (bx / 5) * 2 + m5; // 0..1023
        const int h  = id >> 8;           // 0..3
        const int r0 = (id & 255) * RROWS;
        const float* qh = q + (size_t)h * SJ * DD;
        const float* kh = k + (size_t)h * SJ * DD;

        // ---- Phase A: dots via mfma_f32_16x16x32_bf16 (A rows duplicated 2x),
        // sigmoid -> Smb for the 8 real rows.
        bf16x8 afrag[2];
        {
            const int row   = r0 + ((lane & 15) & 7);  // rows 8..15 dup 0..7
            const int dbase = (lane >> 4) * 8;
            const float* qp = qh + (size_t)row * DD + dbase;
            #pragma unroll
            for (int kk = 0; kk < 2; ++kk) {
                f32x4 v0 = *(const f32x4*)(qp + kk * 32);
                f32x4 v1 = *(const f32x4*)(qp + kk * 32 + 4);
                #pragma unroll
                for (int e = 0; e < 4; ++e) {
                    afrag[kk][e]     = (bf16_t)v0[e];
                    afrag[kk][e + 4] = (bf16_t)v1[e];
                }
            }
        }
        if (tid < RROWS) { pd_in[tid] = 0.f; pd_ex[tid] = 0.f; }
        // wave w computes col tiles in [w*256, (w+1)*256)
        const int rb = (lane >> 4) * 4;   // D row base; rb>=8 -> duplicate rows
        for (int t = 0; t < 16; ++t) {
            const int c0 = w * 256 + t * 16;
            f32x4 acc = {0.f, 0.f, 0.f, 0.f};
            if (use_ws) {
                const size_t fb = (((size_t)h * KT + (c0 >> 4)) * 2) * 64 + lane;
                #pragma unroll
                for (int kk = 0; kk < 2; ++kk) {
                    bf16x8 bfrag = *(const bf16x8*)(wsk + (fb + (size_t)kk * 64) * 8);
                    acc = __builtin_amdgcn_mfma_f32_16x16x32_bf16(afrag[kk], bfrag, acc, 0, 0, 0);
                }
            } else {
                #pragma unroll
                for (int kk = 0; kk < 2; ++kk) {
                    const int col = c0 + (lane & 15);
                    const int db  = kk * 32 + (lane >> 4) * 8;
                    const float* p = kh + (size_t)col * DD + db;
                    f32x4 v0 = *(const f32x4*)(p);
                    f32x4 v1 = *(const f32x4*)(p + 4);
                    bf16x8 bfrag;
                    #pragma unroll
                    for (int e = 0; e < 4; ++e) {
                        bfrag[e]     = (bf16_t)v0[e];
                        bfrag[e + 4] = (bf16_t)v1[e];
                    }
                    acc = __builtin_amdgcn_mfma_f32_16x16x32_bf16(afrag[kk], bfrag, acc, 0, 0, 0);
                }
            }
            if (rb < RROWS) {
                const int ccol = c0 + (lane & 15);
                #pragma unroll
                for (int m = 0; m < 4; ++m)
                    Smb[rb + m][ccol] = (bf16_t)sigmoidf_(acc[m] * 0.125f);
            }
        }
        __syncthreads();

        // ---- Phase B: wave w owns cols [w*256, w*256+256) of all 8 rows.
        // All barriers before any global store.
        const float slope = exp2f(-0.5f * (float)(h + 1));
        const float cabv  = cab[h];
        const int cb = w * 256 + lane * 4;
        u64_t u[RROWS];
        float base_[RROWS];
        #pragma unroll
        for (int rl = 0; rl < RROWS; ++rl) {
            u[rl] = *(const u64_t*)(&Smb[rl][cb]);
            const float i3 = ((bsel(u[rl], 0) + bsel(u[rl], 1))
                            + (bsel(u[rl], 2) + bsel(u[rl], 3)));
            float x = i3;
            #pragma unroll
            for (int d = 1; d < 64; d <<= 1) {
                float y = __shfl_up(x, d);
                if (lane >= d) x += y;
            }
            if (lane == 63) tot[rl][w] = x;
            base_[rl] = x - i3;           // lane-exclusive within segment
        }
        __syncthreads();                  // tot ready
        #pragma unroll
        for (int rl = 0; rl < RROWS; ++rl) {
            float b = 0.f;
            #pragma unroll
            for (int s = 0; s < 7; ++s)
                b += (s < w) ? tot[rl][s] : 0.f;
            base_[rl] += b;               // = P[cb-1] (exclusive total)
            const int rg = r0 + rl, dg = rg + offset;
            const int cin = dg < SJ ? dg : SJ - 1;
            const int cex = (dg - 1) < SJ ? dg - 1 : SJ - 1;
            if (dg >= 0 && (unsigned)(cin - cb) < 4u) {
                const int e = cin - cb;
                float pi = bsel(u[rl], 0);
                if (e > 0) pi += bsel(u[rl], 1);
                if (e > 1) pi += bsel(u[rl], 2);
                if (e > 2) pi += bsel(u[rl], 3);
                pd_in[rl] = base_[rl] + pi;
            }
            if (dg >= 1 && (unsigned)(cex - cb) < 4u) {
                const int e = cex - cb;
                float pi = bsel(u[rl], 0);
                if (e > 0) pi += bsel(u[rl], 1);
                if (e > 1) pi += bsel(u[rl], 2);
                if (e > 2) pi += bsel(u[rl], 3);
                pd_ex[rl] = base_[rl] + pi;
            }
        }
        __syncthreads();                  // pd ready; LAST barrier
        // ---- Phase C: pure store tail, fire-and-forget (nontemporal)
        #pragma unroll
        for (int rl = 0; rl < RROWS; ++rl) {
            const int rg = r0 + rl, dg = rg + offset;
            const float pdin = pd_in[rl];
            const float pdex = pd_ex[rl];
            const bool rpre = dg < prefix;
            const float b  = base_[rl];
            const float i0 = b  + bsel(u[rl], 0);
            const float i1 = i0 + bsel(u[rl], 1);
            const float i2 = i1 + bsel(u[rl], 2);
            const float i3 = i2 + bsel(u[rl], 3);
            const float Pc[4] = {i0, i1, i2, i3};
            const float Pm[4] = {b, i0, i1, i2};
            float* orow = out + ((size_t)h * SJ + rg) * (size_t)SJ;
            f32x4 o;
            #pragma unroll
            for (int e = 0; e < 4; ++e) {
                const int c = cb + e;
                const float cpos = (c > dg) ? -(Pc[e] - pdin)
                                 : (c < dg) ? -(pdex - Pm[e]) : 0.f;
                const bool cross = (c < prefix) != rpre;
                o[e] = cross ? cabv : slope * cpos;
            }
            __builtin_nontemporal_store(o, (f32x4*)(orow + cb));
        }
    } else {
        // ---------------- ALiBi block: 16 rows, pure write (nontemporal) ----
        const int id = (bx / 5) * 3 + (m5 - 2);   // 0..1535
        const int h  = CH + (id >> 7);            // 4..15
        const int r0 = (id & 127) * AROWS;
        const float slope = exp2f(-0.5f * (float)(h + 1));
        const float cabv  = cab[h];
        #pragma unroll
        for (int rr = 0; rr < 2; ++rr) {
            const int rg = r0 + rr * 8 + w;
            const int dg = rg + offset;
            const bool rpre = dg < prefix;
            float* orow = out + ((size_t)h * SJ + rg) * (size_t)SJ;
            #pragma unroll
            for (int s = 0; s < 8; ++s) {
                const int cb = s * 256 + lane * 4;
                f32x4 o;
                #pragma unroll
                for (int e = 0; e < 4; ++e) {
                    const int c = cb + e;
                    const float v = -fabsf((float)(c - dg)) * slope;
                    const bool cross = (c < prefix) != rpre;
                    o[e] = cross ? cabv : v;
                }
                __builtin_nontemporal_store(o, (f32x4*)(orow + cb));
            }
        }
    }
}

extern "C" void kernel_launch(void* const* d_in, const int* in_sizes, int n_in,
                              void* d_out, int out_size, void* d_ws, size_t ws_size,
                              hipStream_t stream) {
    const float* q    = (const float*)d_in[0];
    const float* k    = (const float*)d_in[1];
    const float* cab  = (const float*)d_in[2];
    const int*   offp = (const int*)d_in[5];
    const int*   prep = (const int*)d_in[6];
    float* out = (float*)d_out;
    bf16_t* wsk = (bf16_t*)d_ws;

    const int use_ws = (ws_size >= WSK_BYTES) ? 1 : 0;
    if (use_ws)
        prep_kernel<<<dim3(256), dim3(256), 0, stream>>>(k, wsk);
    fused_kernel<<<dim3(NBLK), dim3(512), 0, stream>>>(q, k, wsk, use_ws,
                                                       cab, offp, prep, out);
}

// Round 13
// 59.654 us; speedup vs baseline: 1.2489x; 1.0697x over previous
//
#include <hip/hip_runtime.h>
#include <hip/hip_bf16.h>

typedef __bf16 bf16_t;
typedef bf16_t bf16x8 __attribute__((ext_vector_type(8)));
typedef float f32x4 __attribute__((ext_vector_type(4)));
typedef unsigned long long u64_t;

#define TH 16     // total heads
#define CH 4      // contextual heads
#define DD 64     // head dim
#define SJ 2048   // seq len (harness-fixed)
#define SP (SJ + 4)                   // padded LDS row stride
#define RROWS 8                       // ctx rows per block -> ~33 KiB LDS
#define KT (SJ/16)                    // 128 col-tiles per head
#define NCTX (CH*SJ/RROWS)            // 1024 ctx blocks
#define AROWS 16                      // alibi rows per block
#define NALIBI ((TH-CH)*SJ/AROWS)     // 1536
#define NBLK (NCTX + NALIBI)          // 2560; period-5: 2 ctx : 3 alibi (5 coprime 8 XCDs)
#define WSK_BYTES ((size_t)CH*KT*2*64*16)     // 1 MiB: K in B-fragment order

__device__ __forceinline__ float sigmoidf_(float x) {
    return __builtin_amdgcn_rcpf(1.0f + __expf(-x));
}

__device__ __forceinline__ float bsel(u64_t u, int e) {
    return __uint_as_float((((unsigned int)(u >> (16 * e)) & 0xffffu) << 16));
}

// Convert ctx-head K to bf16 in MFMA-B-fragment order:
// frag index t = ((h*128 + ct)*2 + kk)*64 + lane ; each frag elem 8 bf16.
__global__ __launch_bounds__(256) void prep_kernel(
    const float* __restrict__ k, bf16_t* __restrict__ wsk)
{
    const int t    = (int)blockIdx.x * 256 + (int)threadIdx.x;  // 0..65535
    const int h    = t >> 14;
    const int ct   = (t >> 7) & 127;
    const int kk   = (t >> 6) & 1;
    const int lane = t & 63;
    const int col  = ct * 16 + (lane & 15);
    const int db   = kk * 32 + (lane >> 4) * 8;
    const float* p = k + ((size_t)h * SJ + col) * DD + db;
    f32x4 v0 = *(const f32x4*)p;
    f32x4 v1 = *(const f32x4*)(p + 4);
    bf16x8 o;
    #pragma unroll
    for (int e = 0; e < 4; ++e) { o[e] = (bf16_t)v0[e]; o[e + 4] = (bf16_t)v1[e]; }
    *(bf16x8*)(wsk + (size_t)t * 8) = o;
}

__global__ __launch_bounds__(512, 4) void fused_kernel(
    const float* __restrict__ q, const float* __restrict__ k,
    const bf16_t* __restrict__ wsk, int use_ws,
    const float* __restrict__ cab, const int* __restrict__ offp,
    const int* __restrict__ prep, float* __restrict__ out)
{
    __shared__ bf16_t Smb[RROWS][SP];     // ~32.1 KiB
    __shared__ float tot[RROWS][8];
    __shared__ float pd_in[RROWS], pd_ex[RROWS];
    const int tid  = (int)threadIdx.x;
    const int lane = tid & 63;
    const int w    = tid >> 6;            // wave 0..7
    const int offset = offp[0];
    const int prefix = prep[0];
    const int bx = (int)blockIdx.x;
    const int m5 = bx % 5;

    if (m5 < 2) {
        // ---------------- contextual strip: 8 rows ----------------
        const int id = (bx / 5) * 2 + m5; // 0..1023
        const int h  = id >> 8;           // 0..3
        const int r0 = (id & 255) * RROWS;
        const float* qh = q + (size_t)h * SJ * DD;
        const float* kh = k + (size_t)h * SJ * DD;

        // ---- Phase A: dots via mfma_f32_16x16x32_bf16 (A rows duplicated 2x),
        // sigmoid -> Smb for the 8 real rows.
        bf16x8 afrag[2];
        {
            const int row   = r0 + ((lane & 15) & 7);  // rows 8..15 dup 0..7
            const int dbase = (lane >> 4) * 8;
            const float* qp = qh + (size_t)row * DD + dbase;
            #pragma unroll
            for (int kk = 0; kk < 2; ++kk) {
                f32x4 v0 = *(const f32x4*)(qp + kk * 32);
                f32x4 v1 = *(const f32x4*)(qp + kk * 32 + 4);
                #pragma unroll
                for (int e = 0; e < 4; ++e) {
                    afrag[kk][e]     = (bf16_t)v0[e];
                    afrag[kk][e + 4] = (bf16_t)v1[e];
                }
            }
        }
        if (tid < RROWS) { pd_in[tid] = 0.f; pd_ex[tid] = 0.f; }
        // wave w computes col tiles in [w*256, (w+1)*256)
        const int rb = (lane >> 4) * 4;   // D row base; rb>=8 -> duplicate rows
        if (use_ws) {
            // ---- fully unrolled, 4-deep register prefetch of B-fragments
            const bf16_t* wb = wsk + ((((size_t)h * KT + w * 16) * 2) * 64 + lane) * 8;
            bf16x8 pf[4][2];
            #pragma unroll
            for (int p = 0; p < 4; ++p) {
                pf[p][0] = *(const bf16x8*)(wb + p * 1024);
                pf[p][1] = *(const bf16x8*)(wb + p * 1024 + 512);
            }
            #pragma unroll
            for (int t = 0; t < 16; ++t) {
                const bf16x8 b0 = pf[t & 3][0];
                const bf16x8 b1 = pf[t & 3][1];
                if (t + 4 < 16) {
                    pf[t & 3][0] = *(const bf16x8*)(wb + (t + 4) * 1024);
                    pf[t & 3][1] = *(const bf16x8*)(wb + (t + 4) * 1024 + 512);
                }
                f32x4 acc = {0.f, 0.f, 0.f, 0.f};
                acc = __builtin_amdgcn_mfma_f32_16x16x32_bf16(afrag[0], b0, acc, 0, 0, 0);
                acc = __builtin_amdgcn_mfma_f32_16x16x32_bf16(afrag[1], b1, acc, 0, 0, 0);
                if (rb < RROWS) {
                    const int ccol = w * 256 + t * 16 + (lane & 15);
                    #pragma unroll
                    for (int m = 0; m < 4; ++m)
                        Smb[rb + m][ccol] = (bf16_t)sigmoidf_(acc[m] * 0.125f);
                }
            }
        } else {
            for (int t = 0; t < 16; ++t) {
                const int c0 = w * 256 + t * 16;
                f32x4 acc = {0.f, 0.f, 0.f, 0.f};
                #pragma unroll
                for (int kk = 0; kk < 2; ++kk) {
                    const int col = c0 + (lane & 15);
                    const int db  = kk * 32 + (lane >> 4) * 8;
                    const float* p = kh + (size_t)col * DD + db;
                    f32x4 v0 = *(const f32x4*)(p);
                    f32x4 v1 = *(const f32x4*)(p + 4);
                    bf16x8 bfrag;
                    #pragma unroll
                    for (int e = 0; e < 4; ++e) {
                        bfrag[e]     = (bf16_t)v0[e];
                        bfrag[e + 4] = (bf16_t)v1[e];
                    }
                    acc = __builtin_amdgcn_mfma_f32_16x16x32_bf16(afrag[kk], bfrag, acc, 0, 0, 0);
                }
                if (rb < RROWS) {
                    const int ccol = c0 + (lane & 15);
                    #pragma unroll
                    for (int m = 0; m < 4; ++m)
                        Smb[rb + m][ccol] = (bf16_t)sigmoidf_(acc[m] * 0.125f);
                }
            }
        }
        __syncthreads();

        // ---- Phase B: wave w owns cols [w*256, w*256+256) of all 8 rows.
        // All barriers before any global store.
        const float slope = exp2f(-0.5f * (float)(h + 1));
        const float cabv  = cab[h];
        const int cb = w * 256 + lane * 4;
        u64_t u[RROWS];
        float base_[RROWS];
        #pragma unroll
        for (int rl = 0; rl < RROWS; ++rl) {
            u[rl] = *(const u64_t*)(&Smb[rl][cb]);
            const float i3 = ((bsel(u[rl], 0) + bsel(u[rl], 1))
                            + (bsel(u[rl], 2) + bsel(u[rl], 3)));
            float x = i3;
            #pragma unroll
            for (int d = 1; d < 64; d <<= 1) {
                float y = __shfl_up(x, d);
                if (lane >= d) x += y;
            }
            if (lane == 63) tot[rl][w] = x;
            base_[rl] = x - i3;           // lane-exclusive within segment
        }
        __syncthreads();                  // tot ready
        #pragma unroll
        for (int rl = 0; rl < RROWS; ++rl) {
            float b = 0.f;
            #pragma unroll
            for (int s = 0; s < 7; ++s)
                b += (s < w) ? tot[rl][s] : 0.f;
            base_[rl] += b;               // = P[cb-1] (exclusive total)
            const int rg = r0 + rl, dg = rg + offset;
            const int cin = dg < SJ ? dg : SJ - 1;
            const int cex = (dg - 1) < SJ ? dg - 1 : SJ - 1;
            if (dg >= 0 && (unsigned)(cin - cb) < 4u) {
                const int e = cin - cb;
                float pi = bsel(u[rl], 0);
                if (e > 0) pi += bsel(u[rl], 1);
                if (e > 1) pi += bsel(u[rl], 2);
                if (e > 2) pi += bsel(u[rl], 3);
                pd_in[rl] = base_[rl] + pi;
            }
            if (dg >= 1 && (unsigned)(cex - cb) < 4u) {
                const int e = cex - cb;
                float pi = bsel(u[rl], 0);
                if (e > 0) pi += bsel(u[rl], 1);
                if (e > 1) pi += bsel(u[rl], 2);
                if (e > 2) pi += bsel(u[rl], 3);
                pd_ex[rl] = base_[rl] + pi;
            }
        }
        __syncthreads();                  // pd ready; LAST barrier
        // ---- Phase C: pure store tail, fire-and-forget
        #pragma unroll
        for (int rl = 0; rl < RROWS; ++rl) {
            const int rg = r0 + rl, dg = rg + offset;
            const float pdin = pd_in[rl];
            const float pdex = pd_ex[rl];
            const bool rpre = dg < prefix;
            const float b  = base_[rl];
            const float i0 = b  + bsel(u[rl], 0);
            const float i1 = i0 + bsel(u[rl], 1);
            const float i2 = i1 + bsel(u[rl], 2);
            const float i3 = i2 + bsel(u[rl], 3);
            const float Pc[4] = {i0, i1, i2, i3};
            const float Pm[4] = {b, i0, i1, i2};
            float* orow = out + ((size_t)h * SJ + rg) * (size_t)SJ;
            f32x4 o;
            #pragma unroll
            for (int e = 0; e < 4; ++e) {
                const int c = cb + e;
                const float cpos = (c > dg) ? -(Pc[e] - pdin)
                                 : (c < dg) ? -(pdex - Pm[e]) : 0.f;
                const bool cross = (c < prefix) != rpre;
                o[e] = cross ? cabv : slope * cpos;
            }
            *(f32x4*)(orow + cb) = o;
        }
    } else {
        // ---------------- ALiBi block: 16 rows, pure write ----------------
        const int id = (bx / 5) * 3 + (m5 - 2);   // 0..1535
        const int h  = CH + (id >> 7);            // 4..15
        const int r0 = (id & 127) * AROWS;
        const float slope = exp2f(-0.5f * (float)(h + 1));
        const float cabv  = cab[h];
        #pragma unroll
        for (int rr = 0; rr < 2; ++rr) {
            const int rg = r0 + rr * 8 + w;
            const int dg = rg + offset;
            const bool rpre = dg < prefix;
            float* orow = out + ((size_t)h * SJ + rg) * (size_t)SJ;
            #pragma unroll
            for (int s = 0; s < 8; ++s) {
                const int cb = s * 256 + lane * 4;
                f32x4 o;
                #pragma unroll
                for (int e = 0; e < 4; ++e) {
                    const int c = cb + e;
                    const float v = -fabsf((float)(c - dg)) * slope;
                    const bool cross = (c < prefix) != rpre;
                    o[e] = cross ? cabv : v;
                }
                *(f32x4*)(orow + cb) = o;
            }
        }
    }
}

extern "C" void kernel_launch(void* const* d_in, const int* in_sizes, int n_in,
                              void* d_out, int out_size, void* d_ws, size_t ws_size,
                              hipStream_t stream) {
    const float* q    = (const float*)d_in[0];
    const float* k    = (const float*)d_in[1];
    const float* cab  = (const float*)d_in[2];
    const int*   offp = (const int*)d_in[5];
    const int*   prep = (const int*)d_in[6];
    float* out = (float*)d_out;
    bf16_t* wsk = (bf16_t*)d_ws;

    const int use_ws = (ws_size >= WSK_BYTES) ? 1 : 0;
    if (use_ws)
        prep_kernel<<<dim3(256), dim3(256), 0, stream>>>(k, wsk);
    fused_kernel<<<dim3(NBLK), dim3(512), 0, stream>>>(q, k, wsk, use_ws,
                                                       cab, offp, prep, out);
}